// Round 1
// baseline (551.798 us; speedup 1.0000x reference)
//
#include <hip/hip_runtime.h>
#include <cstdint>

// LongcatFlashTopkRouter: classify = HS @ W^T (fp32 via split-bf16 MFMA),
// softmax -> +bias -> top-8 -> gather unbiased scores * 1.5.
// Outputs (flat f32): classify [16384*256] | weights [16384*8] | indices-as-float [16384*8]

typedef __attribute__((ext_vector_type(8))) short short8;   // 8 bf16 (4 VGPRs) MFMA A/B frag
typedef __attribute__((ext_vector_type(4))) float f32x4;    // MFMA C/D frag

#define T_TOK   16384
#define DIM     4096
#define NE      256
#define TOPK_N  8

constexpr int BM  = 64;
constexpr int BK  = 64;
constexpr int LDA = BK + 8;   // 72 elems (144 B row stride): spreads frag reads across banks

__device__ __forceinline__ unsigned short f2bf(float f) {
  unsigned int u = __float_as_uint(f);
  u += 0x7fffu + ((u >> 16) & 1u);          // RNE
  return (unsigned short)(u >> 16);
}
__device__ __forceinline__ float bf2f(unsigned short h) {
  return __uint_as_float(((unsigned int)h) << 16);
}

// ---------------- W fp32 -> W_hi / W_lo bf16 (1M elems, one float4/thread) -------------
__global__ __launch_bounds__(256) void convert_w_kernel(
    const float* __restrict__ W,
    unsigned short* __restrict__ Wh,
    unsigned short* __restrict__ Wl) {
  int i = (blockIdx.x * 256 + threadIdx.x) * 4;
  float4 f = *(const float4*)(W + i);
  float fv[4] = {f.x, f.y, f.z, f.w};
  unsigned int hw0, hw1, lw0, lw1;
  unsigned short h[4], l[4];
#pragma unroll
  for (int c = 0; c < 4; ++c) {
    h[c] = f2bf(fv[c]);
    l[c] = f2bf(fv[c] - bf2f(h[c]));
  }
  hw0 = (unsigned)h[0] | ((unsigned)h[1] << 16);
  hw1 = (unsigned)h[2] | ((unsigned)h[3] << 16);
  lw0 = (unsigned)l[0] | ((unsigned)l[1] << 16);
  lw1 = (unsigned)l[2] | ((unsigned)l[3] << 16);
  uint2 hv; hv.x = hw0; hv.y = hw1;
  uint2 lv; lv.x = lw0; lv.y = lw1;
  *(uint2*)(Wh + i) = hv;
  *(uint2*)(Wl + i) = lv;
}

// ---------------- split-bf16 GEMM: C[64 x 256 tile] per block ---------------------------
// 256 threads = 4 waves; wave w covers rows 0..63 x experts [w*64, w*64+64).
// A staged fp32->hi/lo bf16 in LDS (shared by all 4 waves); W frags direct global->reg
// (each W element consumed by exactly one wave -> LDS staging would be pure overhead).
__global__ __launch_bounds__(256) void gemm_router(
    const float* __restrict__ A,
    const unsigned short* __restrict__ Wh,
    const unsigned short* __restrict__ Wl,
    float* __restrict__ C) {
  __shared__ __align__(16) unsigned short Ah[BM * LDA];
  __shared__ __align__(16) unsigned short Al[BM * LDA];

  const int tid  = threadIdx.x;
  const int wave = tid >> 6;
  const int lane = tid & 63;
  const int q    = lane >> 4;     // 0..3  (k quadrant)
  const int ln   = lane & 15;     // 0..15 (m / n within 16-tile)
  const int m_base = blockIdx.x * BM;
  const int n_base = wave * 64;

  // staging map: row = tid>>2 (0..63), 16-float chunk = tid&3
  const int sr = tid >> 2;
  const int sc = tid & 3;
  const float* ap = A + (m_base + sr) * DIM + sc * 16;

  f32x4 acc[4][4] = {};

  for (int k0 = 0; k0 < DIM; k0 += BK) {
    // global loads issued before the barrier (overlap with previous compute)
    float4 a0 = *(const float4*)(ap + k0 + 0);
    float4 a1 = *(const float4*)(ap + k0 + 4);
    float4 a2 = *(const float4*)(ap + k0 + 8);
    float4 a3 = *(const float4*)(ap + k0 + 12);

    __syncthreads();   // previous iteration's frag reads complete before overwrite

    float fv[16] = {a0.x, a0.y, a0.z, a0.w, a1.x, a1.y, a1.z, a1.w,
                    a2.x, a2.y, a2.z, a2.w, a3.x, a3.y, a3.z, a3.w};
    unsigned int hw[8], lw[8];
#pragma unroll
    for (int c = 0; c < 8; ++c) {
      float f0 = fv[2 * c], f1 = fv[2 * c + 1];
      unsigned short h0 = f2bf(f0), h1 = f2bf(f1);
      unsigned short l0 = f2bf(f0 - bf2f(h0)), l1 = f2bf(f1 - bf2f(h1));
      hw[c] = (unsigned)h0 | ((unsigned)h1 << 16);
      lw[c] = (unsigned)l0 | ((unsigned)l1 << 16);
    }
    {
      uint4* dh = (uint4*)&Ah[sr * LDA + sc * 16];
      uint4* dl = (uint4*)&Al[sr * LDA + sc * 16];
      uint4 v0; v0.x = hw[0]; v0.y = hw[1]; v0.z = hw[2]; v0.w = hw[3];
      uint4 v1; v1.x = hw[4]; v1.y = hw[5]; v1.z = hw[6]; v1.w = hw[7];
      uint4 v2; v2.x = lw[0]; v2.y = lw[1]; v2.z = lw[2]; v2.w = lw[3];
      uint4 v3; v3.x = lw[4]; v3.y = lw[5]; v3.z = lw[6]; v3.w = lw[7];
      dh[0] = v0; dh[1] = v1;
      dl[0] = v2; dl[1] = v3;
    }
    __syncthreads();

#pragma unroll
    for (int kk = 0; kk < 2; ++kk) {
      const int kof = k0 + kk * 32 + q * 8;
      short8 bh[4], bl[4];
#pragma unroll
      for (int j = 0; j < 4; ++j) {
        const int e = n_base + j * 16 + ln;
        bh[j] = *(const short8*)(Wh + e * DIM + kof);
        bl[j] = *(const short8*)(Wl + e * DIM + kof);
      }
#pragma unroll
      for (int i = 0; i < 4; ++i) {
        const int aoff = (i * 16 + ln) * LDA + kk * 32 + q * 8;
        short8 ah = *(const short8*)&Ah[aoff];
        short8 al = *(const short8*)&Al[aoff];
#pragma unroll
        for (int j = 0; j < 4; ++j) {
          acc[i][j] = __builtin_amdgcn_mfma_f32_16x16x32_bf16(ah, bh[j], acc[i][j], 0, 0, 0);
          acc[i][j] = __builtin_amdgcn_mfma_f32_16x16x32_bf16(al, bh[j], acc[i][j], 0, 0, 0);
          acc[i][j] = __builtin_amdgcn_mfma_f32_16x16x32_bf16(ah, bl[j], acc[i][j], 0, 0, 0);
        }
      }
    }
  }

  // epilogue: C/D layout col = lane&15, row = (lane>>4)*4 + reg
#pragma unroll
  for (int i = 0; i < 4; ++i)
#pragma unroll
    for (int j = 0; j < 4; ++j)
#pragma unroll
      for (int r = 0; r < 4; ++r) {
        const int row = m_base + i * 16 + q * 4 + r;
        const int col = n_base + j * 16 + ln;
        C[row * NE + col] = acc[i][j][r];
      }
}

// ---------------- softmax + biased top-8 + gather: one wave per token -------------------
__global__ __launch_bounds__(256) void topk_kernel(
    const float* __restrict__ C, const float* __restrict__ bias,
    float* __restrict__ wOut, float* __restrict__ iOut) {
  const int wave = threadIdx.x >> 6;
  const int lane = threadIdx.x & 63;
  const int tok  = blockIdx.x * 4 + wave;

  float4 c4 = *(const float4*)(C + tok * NE + lane * 4);
  float v[4] = {c4.x, c4.y, c4.z, c4.w};

  float mx = fmaxf(fmaxf(v[0], v[1]), fmaxf(v[2], v[3]));
#pragma unroll
  for (int off = 32; off >= 1; off >>= 1) mx = fmaxf(mx, __shfl_xor(mx, off));

  float e0 = __expf(v[0] - mx), e1 = __expf(v[1] - mx);
  float e2 = __expf(v[2] - mx), e3 = __expf(v[3] - mx);
  float sum = e0 + e1 + e2 + e3;
#pragma unroll
  for (int off = 32; off >= 1; off >>= 1) sum += __shfl_xor(sum, off);

  float sc0 = e0 / sum, sc1 = e1 / sum, sc2 = e2 / sum, sc3 = e3 / sum;
  float4 b4 = *(const float4*)(bias + lane * 4);
  float ch0 = sc0 + b4.x, ch1 = sc1 + b4.y, ch2 = sc2 + b4.z, ch3 = sc3 + b4.w;

#pragma unroll
  for (int t = 0; t < TOPK_N; ++t) {
    // local argmax (strict > keeps smallest index on ties)
    float bv = ch0; int bi = 0; float bs = sc0;
    if (ch1 > bv) { bv = ch1; bi = 1; bs = sc1; }
    if (ch2 > bv) { bv = ch2; bi = 2; bs = sc2; }
    if (ch3 > bv) { bv = ch3; bi = 3; bs = sc3; }
    int be = lane * 4 + bi;
    // wave butterfly all-reduce argmax, tie -> smaller expert index (matches lax.top_k)
#pragma unroll
    for (int off = 32; off >= 1; off >>= 1) {
      float ov = __shfl_xor(bv, off);
      int   oe = __shfl_xor(be, off);
      float os = __shfl_xor(bs, off);
      if (ov > bv || (ov == bv && oe < be)) { bv = ov; be = oe; bs = os; }
    }
    if (lane == 0) {
      wOut[tok * TOPK_N + t] = bs * 1.5f;
      iOut[tok * TOPK_N + t] = (float)be;   // flat out buffer is read as f32
    }
    // mask the winner in its owner lane
    bool own = (be >> 2) == lane;
    int  lb  = be & 3;
    if (own && lb == 0) ch0 = -INFINITY;
    if (own && lb == 1) ch1 = -INFINITY;
    if (own && lb == 2) ch2 = -INFINITY;
    if (own && lb == 3) ch3 = -INFINITY;
  }
}

extern "C" void kernel_launch(void* const* d_in, const int* in_sizes, int n_in,
                              void* d_out, int out_size, void* d_ws, size_t ws_size,
                              hipStream_t stream) {
  const float* hs   = (const float*)d_in[0];   // [16384, 4096] f32
  const float* W    = (const float*)d_in[1];   // [256, 4096]   f32
  const float* bias = (const float*)d_in[2];   // [256]         f32

  float* out      = (float*)d_out;
  float* classify = out;                               // 16384*256
  float* wOut     = out + (size_t)T_TOK * NE;          // 16384*8
  float* iOut     = wOut + (size_t)T_TOK * TOPK_N;     // 16384*8

  unsigned short* Wh = (unsigned short*)d_ws;          // 2 MB
  unsigned short* Wl = Wh + (size_t)NE * DIM;          // 2 MB  (needs ws_size >= 4 MB)

  convert_w_kernel<<<NE * DIM / 4 / 256, 256, 0, stream>>>(W, Wh, Wl);
  gemm_router<<<T_TOK / BM, 256, 0, stream>>>(hs, Wh, Wl, classify);
  topk_kernel<<<T_TOK / 4, 256, 0, stream>>>(classify, bias, wOut, iOut);
}

// Round 2
// 543.774 us; speedup vs baseline: 1.0148x; 1.0148x over previous
//
#include <hip/hip_runtime.h>
#include <cstdint>

// LongcatFlashTopkRouter: classify = HS @ W^T (fp32 via split-bf16 3-product MFMA),
// softmax -> +bias -> top-8 -> gather unbiased scores * 1.5.
// Outputs (flat f32): classify [16384*256] | weights [16384*8] | indices-as-float [16384*8]
//
// R2: W pre-packed fragment-major + lane-coalesced; 1024-thread GEMM blocks
// (16 waves = 4 row-groups x 4 col-groups, BM=64, BK=32); B double-buffered in
// LDS (64 KB), A VGPR-direct with in-register fp32->hi/lo bf16 split; single
// __syncthreads per k-chunk with all next-chunk loads in flight across compute.

typedef __attribute__((ext_vector_type(8))) short short8;   // 8 bf16 MFMA A/B frag
typedef __attribute__((ext_vector_type(4))) float f32x4;    // MFMA C/D frag

#define T_TOK   16384
#define DIM     4096
#define NE      256
#define TOPK_N  8
#define NKC     128      // 128 k-chunks of 32

__device__ __forceinline__ unsigned short f2bf(float f) {
  unsigned int u = __float_as_uint(f);
  u += 0x7fffu + ((u >> 16) & 1u);          // RNE
  return (unsigned short)(u >> 16);
}
__device__ __forceinline__ float bf2f(unsigned short h) {
  return __uint_as_float(((unsigned int)h) << 16);
}

// ---- pack W fp32 -> fragment-major hi/lo bf16 ------------------------------------
// Whp/Wlp[((g*128 + c)*64 + q*16 + n)*8 + j] = hi/lo(W[g*16+n][c*32 + q*8 + j])
// so GEMM lane l = q*16+n of expert-group g reads its whole frag as one 16 B load.
__global__ __launch_bounds__(256) void convert_w_kernel(
    const float* __restrict__ W,
    unsigned short* __restrict__ Whp,
    unsigned short* __restrict__ Wlp) {
  const int tg = blockIdx.x * 256 + threadIdx.x;   // 131072 threads: e * 512 + k8
  const int e = tg >> 9, k8 = tg & 511;
  const int g = e >> 4, n = e & 15, c = k8 >> 2, q = k8 & 3;
  const float* src = W + (size_t)e * DIM + k8 * 8;
  float4 f0 = *(const float4*)src;
  float4 f1 = *(const float4*)(src + 4);
  float fv[8] = {f0.x, f0.y, f0.z, f0.w, f1.x, f1.y, f1.z, f1.w};
  unsigned short hh[8], ll[8];
#pragma unroll
  for (int x = 0; x < 8; ++x) {
    hh[x] = f2bf(fv[x]);
    ll[x] = f2bf(fv[x] - bf2f(hh[x]));
  }
  uint4 hv, lv;
  hv.x = (unsigned)hh[0] | ((unsigned)hh[1] << 16);
  hv.y = (unsigned)hh[2] | ((unsigned)hh[3] << 16);
  hv.z = (unsigned)hh[4] | ((unsigned)hh[5] << 16);
  hv.w = (unsigned)hh[6] | ((unsigned)hh[7] << 16);
  lv.x = (unsigned)ll[0] | ((unsigned)ll[1] << 16);
  lv.y = (unsigned)ll[2] | ((unsigned)ll[3] << 16);
  lv.z = (unsigned)ll[4] | ((unsigned)ll[5] << 16);
  lv.w = (unsigned)ll[6] | ((unsigned)ll[7] << 16);
  const size_t dst = ((size_t)(g * 128 + c) * 64 + q * 16 + n) * 8;
  *(uint4*)(Whp + dst) = hv;
  *(uint4*)(Wlp + dst) = lv;
}

// ---- GEMM: 256 blocks x 1024 threads; block = 64 rows x all 256 experts ----------
__global__ __launch_bounds__(1024, 4) void gemm_router(
    const float* __restrict__ A,
    const unsigned short* __restrict__ Whp,
    const unsigned short* __restrict__ Wlp,
    float* __restrict__ C) {
  // [buf][expert-group g][hi/lo][lane][8 bf16] = 64 KB total
  __shared__ __align__(16) unsigned short Bsh[2][16][2][64][8];

  const int tid  = threadIdx.x;
  const int w    = tid >> 6;        // wave 0..15
  const int lane = tid & 63;
  const int rg   = w >> 2;          // row-group 0..3 (16 rows each)
  const int cg   = w & 3;           // col-group 0..3 (64 experts each)
  const int q    = lane >> 4;       // k-quadrant 0..3
  const int mn   = lane & 15;       // m (A row) / n (expert) within 16-tile
  const int m_base = blockIdx.x * 64;

  // A: this lane's frag source = row (rg*16+mn), k = c*32 + q*8 .. +8  (8 fp32)
  const float* arow = A + (size_t)(m_base + rg * 16 + mn) * DIM + q * 8;
  // B: wave w stages expert-group g = w; per-lane-coalesced 16 B chunks
  const unsigned short* bsrch = Whp + (size_t)w * 65536 + lane * 8;
  const unsigned short* bsrcl = Wlp + (size_t)w * 65536 + lane * 8;

  // prologue: chunk 0 into regs, stage B into buf 0
  float4 a0n = *(const float4*)(arow);
  float4 a1n = *(const float4*)(arow + 4);
  uint4  bhn = *(const uint4*)(bsrch);
  uint4  bln = *(const uint4*)(bsrcl);
  *(uint4*)&Bsh[0][w][0][lane][0] = bhn;
  *(uint4*)&Bsh[0][w][1][lane][0] = bln;

  f32x4 acc[4] = {};

  for (int it = 0; it < NKC; ++it) {
    const int cur = it & 1;
    float4 a0 = a0n, a1 = a1n;
    __syncthreads();                       // buf[cur] ready; prev readers done

    // issue next-chunk loads: in flight across this chunk's whole compute phase
    const int nk = (it < NKC - 1) ? it + 1 : it;
    a0n = *(const float4*)(arow + nk * 32);
    a1n = *(const float4*)(arow + nk * 32 + 4);
    bhn = *(const uint4*)(bsrch + nk * 512);
    bln = *(const uint4*)(bsrcl + nk * 512);

    // split current A regs -> hi/lo bf16 frags
    float fa[8] = {a0.x, a0.y, a0.z, a0.w, a1.x, a1.y, a1.z, a1.w};
    short8 ah, al;
#pragma unroll
    for (int x = 0; x < 8; ++x) {
      unsigned short h = f2bf(fa[x]);
      ah[x] = (short)h;
      al[x] = (short)f2bf(fa[x] - bf2f(h));
    }

#pragma unroll
    for (int j = 0; j < 4; ++j) {
      short8 bh = *(const short8*)&Bsh[cur][cg * 4 + j][0][lane][0];
      short8 bl = *(const short8*)&Bsh[cur][cg * 4 + j][1][lane][0];
      acc[j] = __builtin_amdgcn_mfma_f32_16x16x32_bf16(ah, bh, acc[j], 0, 0, 0);
      acc[j] = __builtin_amdgcn_mfma_f32_16x16x32_bf16(al, bh, acc[j], 0, 0, 0);
      acc[j] = __builtin_amdgcn_mfma_f32_16x16x32_bf16(ah, bl, acc[j], 0, 0, 0);
    }

    // stage next chunk into the other buffer (readers of it sit behind next barrier)
    if (it < NKC - 1) {
      *(uint4*)&Bsh[cur ^ 1][w][0][lane][0] = bhn;
      *(uint4*)&Bsh[cur ^ 1][w][1][lane][0] = bln;
    }
  }

  // epilogue: C/D layout col = lane&15, row = (lane>>4)*4 + reg  (verified R1)
#pragma unroll
  for (int j = 0; j < 4; ++j)
#pragma unroll
    for (int r = 0; r < 4; ++r) {
      const int row = m_base + rg * 16 + q * 4 + r;
      const int col = cg * 64 + j * 16 + mn;
      C[(size_t)row * NE + col] = acc[j][r];
    }
}

// ---- softmax + biased top-8 + gather: one wave per token (unchanged, passed R1) --
__global__ __launch_bounds__(256) void topk_kernel(
    const float* __restrict__ C, const float* __restrict__ bias,
    float* __restrict__ wOut, float* __restrict__ iOut) {
  const int wave = threadIdx.x >> 6;
  const int lane = threadIdx.x & 63;
  const int tok  = blockIdx.x * 4 + wave;

  float4 c4 = *(const float4*)(C + (size_t)tok * NE + lane * 4);
  float v[4] = {c4.x, c4.y, c4.z, c4.w};

  float mx = fmaxf(fmaxf(v[0], v[1]), fmaxf(v[2], v[3]));
#pragma unroll
  for (int off = 32; off >= 1; off >>= 1) mx = fmaxf(mx, __shfl_xor(mx, off));

  float e0 = __expf(v[0] - mx), e1 = __expf(v[1] - mx);
  float e2 = __expf(v[2] - mx), e3 = __expf(v[3] - mx);
  float sum = e0 + e1 + e2 + e3;
#pragma unroll
  for (int off = 32; off >= 1; off >>= 1) sum += __shfl_xor(sum, off);

  float sc0 = e0 / sum, sc1 = e1 / sum, sc2 = e2 / sum, sc3 = e3 / sum;
  float4 b4 = *(const float4*)(bias + lane * 4);
  float ch0 = sc0 + b4.x, ch1 = sc1 + b4.y, ch2 = sc2 + b4.z, ch3 = sc3 + b4.w;

#pragma unroll
  for (int t = 0; t < TOPK_N; ++t) {
    float bv = ch0; int bi = 0; float bs = sc0;
    if (ch1 > bv) { bv = ch1; bi = 1; bs = sc1; }
    if (ch2 > bv) { bv = ch2; bi = 2; bs = sc2; }
    if (ch3 > bv) { bv = ch3; bi = 3; bs = sc3; }
    int be = lane * 4 + bi;
#pragma unroll
    for (int off = 32; off >= 1; off >>= 1) {
      float ov = __shfl_xor(bv, off);
      int   oe = __shfl_xor(be, off);
      float os = __shfl_xor(bs, off);
      if (ov > bv || (ov == bv && oe < be)) { bv = ov; be = oe; bs = os; }
    }
    if (lane == 0) {
      wOut[tok * TOPK_N + t] = bs * 1.5f;
      iOut[tok * TOPK_N + t] = (float)be;
    }
    bool own = (be >> 2) == lane;
    int  lb  = be & 3;
    if (own && lb == 0) ch0 = -INFINITY;
    if (own && lb == 1) ch1 = -INFINITY;
    if (own && lb == 2) ch2 = -INFINITY;
    if (own && lb == 3) ch3 = -INFINITY;
  }
}

extern "C" void kernel_launch(void* const* d_in, const int* in_sizes, int n_in,
                              void* d_out, int out_size, void* d_ws, size_t ws_size,
                              hipStream_t stream) {
  const float* hs   = (const float*)d_in[0];   // [16384, 4096] f32
  const float* W    = (const float*)d_in[1];   // [256, 4096]   f32
  const float* bias = (const float*)d_in[2];   // [256]         f32

  float* out      = (float*)d_out;
  float* classify = out;                               // 16384*256
  float* wOut     = out + (size_t)T_TOK * NE;          // 16384*8
  float* iOut     = wOut + (size_t)T_TOK * TOPK_N;     // 16384*8

  unsigned short* Whp = (unsigned short*)d_ws;         // 2 MB packed hi
  unsigned short* Wlp = Whp + (size_t)NE * DIM;        // 2 MB packed lo

  convert_w_kernel<<<(NE * DIM / 8) / 256, 256, 0, stream>>>(W, Whp, Wlp);
  gemm_router<<<T_TOK / 64, 1024, 0, stream>>>(hs, Whp, Wlp, classify);
  topk_kernel<<<T_TOK / 4, 256, 0, stream>>>(classify, bias, wOut, iOut);
}

// Round 3
// 486.643 us; speedup vs baseline: 1.1339x; 1.1174x over previous
//
#include <hip/hip_runtime.h>
#include <cstdint>

// LongcatFlashTopkRouter R3.
// classify = HS @ W^T (fp32 via split-bf16 3-product MFMA 16x16x32), then
// softmax -> +bias -> top-8 -> gather unbiased scores * 1.5.
// Outputs (flat f32): classify [16384*256] | weights [16384*8] | indices [16384*8]
//
// GEMM: grid (2 expert-halves, 256 row-bands) x 256 thr (4 waves).
// Wave w owns 32 experts (2 n-tiles of 16) x 64 rows (4 m-tiles of 16).
// A: global->reg->split hi/lo bf16->LDS (lane-major frag layout, conflict-free,
//    double-buffered 2x32KB, ONE barrier/chunk of 128k, next-chunk loads issued
//    AFTER the barrier so the vmcnt drain never waits on fresh HBM).
// B: pre-packed fragment-major in d_ws, loaded straight to regs (L2-resident),
//    1-step register prefetch. 2 blocks/CU stagger their barriers.

typedef __attribute__((ext_vector_type(8))) short short8;   // 8 bf16 MFMA A/B frag
typedef __attribute__((ext_vector_type(4))) float f32x4;    // MFMA C/D frag

#define T_TOK  16384
#define DIM    4096
#define NE     256
#define TOPK_N 8

__device__ __forceinline__ unsigned short f2bf(float f) {
  unsigned int u = __float_as_uint(f);
  u += 0x7fffu + ((u >> 16) & 1u);          // RNE
  return (unsigned short)(u >> 16);
}
__device__ __forceinline__ float bf2f(unsigned short h) {
  return __uint_as_float(((unsigned int)h) << 16);
}
__device__ __forceinline__ void split8(float4 a, float4 b, uint4& hv, uint4& lv) {
  float fv[8] = {a.x, a.y, a.z, a.w, b.x, b.y, b.z, b.w};
  unsigned short hh[8], ll[8];
#pragma unroll
  for (int x = 0; x < 8; ++x) {
    hh[x] = f2bf(fv[x]);
    ll[x] = f2bf(fv[x] - bf2f(hh[x]));
  }
  hv.x = (unsigned)hh[0] | ((unsigned)hh[1] << 16);
  hv.y = (unsigned)hh[2] | ((unsigned)hh[3] << 16);
  hv.z = (unsigned)hh[4] | ((unsigned)hh[5] << 16);
  hv.w = (unsigned)hh[6] | ((unsigned)hh[7] << 16);
  lv.x = (unsigned)ll[0] | ((unsigned)ll[1] << 16);
  lv.y = (unsigned)ll[2] | ((unsigned)ll[3] << 16);
  lv.z = (unsigned)ll[4] | ((unsigned)ll[5] << 16);
  lv.w = (unsigned)ll[6] | ((unsigned)ll[7] << 16);
}

// ---- pack W fp32 -> fragment-major hi/lo bf16 -----------------------------------
// Wp[((nt*128 + sg)*64 + lane)*8 + j] where lane = q*16 + (e&15), nt = e>>4,
// sg = k>>5, q = (k>>3)&3, j = k&7  -> B-frag load is one coalesced 16B/lane.
__global__ __launch_bounds__(256) void convert_w_kernel(
    const float* __restrict__ W,
    unsigned short* __restrict__ Whp,
    unsigned short* __restrict__ Wlp) {
  const int t = blockIdx.x * 256 + threadIdx.x;   // 131072 threads
  const int e = t >> 9, k8 = t & 511;             // k8 = 8-float group
  const int nt = e >> 4, col = e & 15;
  const int sg = k8 >> 2, q = k8 & 3;
  const int lane = q * 16 + col;
  const float* src = W + (size_t)e * DIM + k8 * 8;
  float4 f0 = *(const float4*)src;
  float4 f1 = *(const float4*)(src + 4);
  uint4 hv, lv;
  split8(f0, f1, hv, lv);
  const size_t dst = ((size_t)(nt * 128 + sg) * 64 + lane) * 8;
  *(uint4*)(Whp + dst) = hv;
  *(uint4*)(Wlp + dst) = lv;
}

// ---- GEMM ------------------------------------------------------------------------
__global__ __launch_bounds__(256, 2) void gemm_router(
    const float* __restrict__ A,
    const unsigned short* __restrict__ Whp,
    const unsigned short* __restrict__ Wlp,
    float* __restrict__ C) {
  // [buf][hi/lo][seg' = rt*4+sq (16)][lane (64)][8 bf16] = 64 KB, lane-major:
  // frag read AND staging write are contiguous 1024 B per wave instr.
  __shared__ __align__(16) unsigned short Ash[2][2][16][64][8];

  const int tid = threadIdx.x;
  const int w   = tid >> 6;          // wave 0..3 (also the k-quarter it stages)
  const int l   = tid & 63;
  const int q   = l >> 4;            // quad within frag
  const int c16 = l & 15;
  const int eh   = blockIdx.x;       // expert half 0..1
  const int band = blockIdx.y;       // 64-row band 0..255
  const int g32  = eh * 4 + w;       // this wave's 32-expert group

  // A staging: thread covers rows i*16 + (l&15), k-offset w*32 + (l>>4)*8 (+jh*4)
  const float* abase = A + (size_t)band * 64 * DIM;
  const int srow = c16;
  const int koff = w * 32 + q * 8;

  // B: packed frag pointers for this wave's two 16-expert tiles
  const unsigned short* pWh0 = Whp + (size_t)(g32 * 2    ) * 65536 + (size_t)l * 8;
  const unsigned short* pWl0 = Wlp + (size_t)(g32 * 2    ) * 65536 + (size_t)l * 8;
  const unsigned short* pWh1 = Whp + (size_t)(g32 * 2 + 1) * 65536 + (size_t)l * 8;
  const unsigned short* pWl1 = Wlp + (size_t)(g32 * 2 + 1) * 65536 + (size_t)l * 8;

  f32x4 acc[4][2] = {};              // [m-tile rt][n-tile nt]
  float4 ar[8];                      // chunk staging regs (4 rows x 8 floats)

  // prologue: chunk 0 A regs + B step 0 prefetch
#pragma unroll
  for (int i = 0; i < 4; ++i) {
    const float* rp = abase + (size_t)(i * 16 + srow) * DIM + koff;
    ar[i * 2]     = *(const float4*)(rp);
    ar[i * 2 + 1] = *(const float4*)(rp + 4);
  }
  uint4 nb0h = *(const uint4*)(pWh0);
  uint4 nb0l = *(const uint4*)(pWl0);
  uint4 nb1h = *(const uint4*)(pWh1);
  uint4 nb1l = *(const uint4*)(pWl1);

  for (int c = 0; c < 32; ++c) {
    const int buf = c & 1;
    // convert this chunk's regs -> LDS (contiguous 1024B wave writes)
#pragma unroll
    for (int i = 0; i < 4; ++i) {
      uint4 hv, lv;
      split8(ar[i * 2], ar[i * 2 + 1], hv, lv);
      *(uint4*)&Ash[buf][0][i * 4 + w][l][0] = hv;
      *(uint4*)&Ash[buf][1][i * 4 + w][l][0] = lv;
    }
    __syncthreads();   // drains ds_writes + old B prefetch (cheap) — no fresh HBM

    // issue next chunk's A loads now: full compute phase to land
    if (c < 31) {
      const int k0n = (c + 1) * 128;
#pragma unroll
      for (int i = 0; i < 4; ++i) {
        const float* rp = abase + (size_t)(i * 16 + srow) * DIM + k0n + koff;
        ar[i * 2]     = *(const float4*)(rp);
        ar[i * 2 + 1] = *(const float4*)(rp + 4);
      }
    }

#pragma unroll
    for (int s = 0; s < 4; ++s) {
      uint4 b0h = nb0h, b0l = nb0l, b1h = nb1h, b1l = nb1l;
      const int gs = c * 4 + s + 1;        // next k32-step, global
      if (gs < 128) {
        nb0h = *(const uint4*)(pWh0 + (size_t)gs * 512);
        nb0l = *(const uint4*)(pWl0 + (size_t)gs * 512);
        nb1h = *(const uint4*)(pWh1 + (size_t)gs * 512);
        nb1l = *(const uint4*)(pWl1 + (size_t)gs * 512);
      }
      short8 ah[4], al[4];
#pragma unroll
      for (int rt = 0; rt < 4; ++rt) {
        ah[rt] = *(const short8*)&Ash[buf][0][rt * 4 + s][l][0];
        al[rt] = *(const short8*)&Ash[buf][1][rt * 4 + s][l][0];
      }
      short8 B0h = *(const short8*)&b0h;
      short8 B0l = *(const short8*)&b0l;
      short8 B1h = *(const short8*)&b1h;
      short8 B1l = *(const short8*)&b1l;
#pragma unroll
      for (int rt = 0; rt < 4; ++rt) {
        acc[rt][0] = __builtin_amdgcn_mfma_f32_16x16x32_bf16(ah[rt], B0h, acc[rt][0], 0, 0, 0);
        acc[rt][1] = __builtin_amdgcn_mfma_f32_16x16x32_bf16(ah[rt], B1h, acc[rt][1], 0, 0, 0);
      }
#pragma unroll
      for (int rt = 0; rt < 4; ++rt) {
        acc[rt][0] = __builtin_amdgcn_mfma_f32_16x16x32_bf16(al[rt], B0h, acc[rt][0], 0, 0, 0);
        acc[rt][1] = __builtin_amdgcn_mfma_f32_16x16x32_bf16(al[rt], B1h, acc[rt][1], 0, 0, 0);
      }
#pragma unroll
      for (int rt = 0; rt < 4; ++rt) {
        acc[rt][0] = __builtin_amdgcn_mfma_f32_16x16x32_bf16(ah[rt], B0l, acc[rt][0], 0, 0, 0);
        acc[rt][1] = __builtin_amdgcn_mfma_f32_16x16x32_bf16(ah[rt], B1l, acc[rt][1], 0, 0, 0);
      }
    }
  }

  // epilogue: C/D layout col = lane&15, row = (lane>>4)*4 + reg (verified R1/R2)
#pragma unroll
  for (int rt = 0; rt < 4; ++rt)
#pragma unroll
    for (int nt = 0; nt < 2; ++nt)
#pragma unroll
      for (int r = 0; r < 4; ++r) {
        const int row = band * 64 + rt * 16 + q * 4 + r;
        const int col = g32 * 32 + nt * 16 + c16;
        C[(size_t)row * NE + col] = acc[rt][nt][r];
      }
}

// ---- softmax + biased top-8 + gather: one wave per token (passed R1/R2) ----------
__global__ __launch_bounds__(256) void topk_kernel(
    const float* __restrict__ C, const float* __restrict__ bias,
    float* __restrict__ wOut, float* __restrict__ iOut) {
  const int wave = threadIdx.x >> 6;
  const int lane = threadIdx.x & 63;
  const int tok  = blockIdx.x * 4 + wave;

  float4 c4 = *(const float4*)(C + (size_t)tok * NE + lane * 4);
  float v[4] = {c4.x, c4.y, c4.z, c4.w};

  float mx = fmaxf(fmaxf(v[0], v[1]), fmaxf(v[2], v[3]));
#pragma unroll
  for (int off = 32; off >= 1; off >>= 1) mx = fmaxf(mx, __shfl_xor(mx, off));

  float e0 = __expf(v[0] - mx), e1 = __expf(v[1] - mx);
  float e2 = __expf(v[2] - mx), e3 = __expf(v[3] - mx);
  float sum = e0 + e1 + e2 + e3;
#pragma unroll
  for (int off = 32; off >= 1; off >>= 1) sum += __shfl_xor(sum, off);

  float sc0 = e0 / sum, sc1 = e1 / sum, sc2 = e2 / sum, sc3 = e3 / sum;
  float4 b4 = *(const float4*)(bias + lane * 4);
  float ch0 = sc0 + b4.x, ch1 = sc1 + b4.y, ch2 = sc2 + b4.z, ch3 = sc3 + b4.w;

#pragma unroll
  for (int t = 0; t < TOPK_N; ++t) {
    float bv = ch0; int bi = 0; float bs = sc0;
    if (ch1 > bv) { bv = ch1; bi = 1; bs = sc1; }
    if (ch2 > bv) { bv = ch2; bi = 2; bs = sc2; }
    if (ch3 > bv) { bv = ch3; bi = 3; bs = sc3; }
    int be = lane * 4 + bi;
#pragma unroll
    for (int off = 32; off >= 1; off >>= 1) {
      float ov = __shfl_xor(bv, off);
      int   oe = __shfl_xor(be, off);
      float os = __shfl_xor(bs, off);
      if (ov > bv || (ov == bv && oe < be)) { bv = ov; be = oe; bs = os; }
    }
    if (lane == 0) {
      wOut[tok * TOPK_N + t] = bs * 1.5f;
      iOut[tok * TOPK_N + t] = (float)be;
    }
    bool own = (be >> 2) == lane;
    int  lb  = be & 3;
    if (own && lb == 0) ch0 = -INFINITY;
    if (own && lb == 1) ch1 = -INFINITY;
    if (own && lb == 2) ch2 = -INFINITY;
    if (own && lb == 3) ch3 = -INFINITY;
  }
}

extern "C" void kernel_launch(void* const* d_in, const int* in_sizes, int n_in,
                              void* d_out, int out_size, void* d_ws, size_t ws_size,
                              hipStream_t stream) {
  const float* hs   = (const float*)d_in[0];   // [16384, 4096] f32
  const float* W    = (const float*)d_in[1];   // [256, 4096]   f32
  const float* bias = (const float*)d_in[2];   // [256]         f32

  float* out      = (float*)d_out;
  float* classify = out;                               // 16384*256
  float* wOut     = out + (size_t)T_TOK * NE;          // 16384*8
  float* iOut     = wOut + (size_t)T_TOK * TOPK_N;     // 16384*8

  unsigned short* Whp = (unsigned short*)d_ws;         // 2 MB packed hi
  unsigned short* Wlp = Whp + (size_t)NE * DIM;        // 2 MB packed lo

  convert_w_kernel<<<(NE * DIM / 8) / 256, 256, 0, stream>>>(W, Whp, Wlp);
  gemm_router<<<dim3(2, 256), 256, 0, stream>>>(hs, Whp, Wlp, classify);
  topk_kernel<<<T_TOK / 4, 256, 0, stream>>>(classify, bias, wOut, iOut);
}

// Round 4
// 456.904 us; speedup vs baseline: 1.2077x; 1.0651x over previous
//
#include <hip/hip_runtime.h>
#include <hip/hip_bf16.h>
#include <cstdint>

// LongcatFlashTopkRouter R4.
// classify = HS @ W^T (fp32 via split-bf16 3-product MFMA 32x32x16), then
// softmax -> +bias -> top-8 -> gather unbiased scores * 1.5.
// Outputs (flat f32): classify [16384*256] | weights [16384*8] | indices [16384*8]
//
// GEMM: grid 512 = 2 k-halves x 256 row-bands, 256 thr (4 waves). Block tile
// M=64 x E=256 x K=2048. Wave w: 2 m-tiles x 2 n-tiles (nt=2w,2w+1) -> 64 acc.
// A: global->reg->cvt_pk split hi/lo bf16->LDS (frag-major, conflict-free,
//    dbuf 2x32KB, ONE barrier per 128k chunk, prefetch a full chunk ahead).
// B: pre-packed fragment-major (d_ws), direct-to-reg, depth-2 prefetch.
// K-halves combine via unsafeAtomicAdd onto memset-zeroed classify.

typedef __attribute__((ext_vector_type(8))) short short8;    // 8 bf16 MFMA A/B frag
typedef __attribute__((ext_vector_type(16))) float f32x16;   // 32x32 MFMA C/D frag

#define T_TOK  16384
#define DIM    4096
#define NE     256
#define TOPK_N 8

__device__ __forceinline__ float bf2f_u(unsigned short h) {
  return __uint_as_float(((unsigned int)h) << 16);
}
// pack 2 floats -> 2 bf16 RNE in one u32 (f0 low, f1 high); v_cvt_pk_bf16_f32 on gfx950
__device__ __forceinline__ unsigned cvt_pk2(float f0, float f1) {
  __hip_bfloat162 h2 = __float22bfloat162_rn(float2{f0, f1});
  unsigned u;
  __builtin_memcpy(&u, &h2, 4);
  return u;
}
// split 8 floats -> hi uint4 + lo uint4 (Markidis residual, exact)
__device__ __forceinline__ void split8(const float* f, uint4& hv, uint4& lv) {
  unsigned h[4], l[4];
#pragma unroll
  for (int c = 0; c < 4; ++c) {
    float a = f[2 * c], b = f[2 * c + 1];
    h[c] = cvt_pk2(a, b);
    float ra = a - bf2f_u((unsigned short)(h[c] & 0xffffu));
    float rb = b - bf2f_u((unsigned short)(h[c] >> 16));
    l[c] = cvt_pk2(ra, rb);
  }
  hv = uint4{h[0], h[1], h[2], h[3]};
  lv = uint4{l[0], l[1], l[2], l[3]};
}

// ---- pack W fp32 -> fragment-major hi/lo bf16 for 32x32x16 B-frags ---------------
// Wp[((nt*256 + s)*64 + h*32 + col)*8 + j] = W[nt*32+col][s*16 + h*8 + j]
__global__ __launch_bounds__(256) void convert_w_kernel(
    const float* __restrict__ W,
    unsigned short* __restrict__ Whp,
    unsigned short* __restrict__ Wlp) {
  const int t = blockIdx.x * 256 + threadIdx.x;   // 131072 threads
  const int e = t >> 9, k8 = t & 511;
  const int nt = e >> 5, col = e & 31;
  const int s = k8 >> 1, h = k8 & 1;
  const float* src = W + (size_t)e * DIM + k8 * 8;
  float f[8];
  *(float4*)(f)     = *(const float4*)src;
  *(float4*)(f + 4) = *(const float4*)(src + 4);
  uint4 hv, lv;
  split8(f, hv, lv);
  const size_t dst = ((size_t)(nt * 256 + s) * 64 + h * 32 + col) * 8;
  *(uint4*)(Whp + dst) = hv;
  *(uint4*)(Wlp + dst) = lv;
}

// ---- GEMM ------------------------------------------------------------------------
__device__ __forceinline__ f32x16 mfma32(short8 a, short8 b, f32x16 c) {
  return __builtin_amdgcn_mfma_f32_32x32x16_bf16(a, b, c, 0, 0, 0);
}

__global__ __launch_bounds__(256, 2) void gemm_router(
    const float* __restrict__ A,
    const unsigned short* __restrict__ Whp,
    const unsigned short* __restrict__ Wlp,
    float* __restrict__ C) {
  // [buf][hilo][mt][ks(8)][lane][8] = 64 KB; frag read/write contiguous per wave
  __shared__ __align__(16) unsigned short Ash[2][2][2][8][64][8];

  const int tid  = threadIdx.x;
  const int w    = tid >> 6, l = tid & 63;
  const int band = blockIdx.x & 255;
  const int kh   = blockIdx.x >> 8;            // k-half 0..1
  const size_t kbase = (size_t)kh * 2048;

  // staging: thread covers row = tid>>2, k-window (tid&3)*32 .. +32 (2 ks steps)
  const int srow = tid >> 2, kg = tid & 3;
  const int smt = srow >> 5, sr = srow & 31;
  const float* ap = A + (size_t)(band * 64 + srow) * DIM + kbase + kg * 32;

  // B packed pointers: wave w owns nt = 2w, 2w+1; k-step offset kh*128
  const unsigned short* ph0 = Whp + ((size_t)(2 * w)     * 256 + kh * 128) * 512 + (size_t)l * 8;
  const unsigned short* pl0 = Wlp + ((size_t)(2 * w)     * 256 + kh * 128) * 512 + (size_t)l * 8;
  const unsigned short* ph1 = Whp + ((size_t)(2 * w + 1) * 256 + kh * 128) * 512 + (size_t)l * 8;
  const unsigned short* pl1 = Wlp + ((size_t)(2 * w + 1) * 256 + kh * 128) * 512 + (size_t)l * 8;

  f32x16 acc00 = {}, acc01 = {}, acc10 = {}, acc11 = {};
  float ar[32];

  // prologue: chunk 0 -> LDS buf0; chunk 1 -> regs; B depth-2 prefetch
#pragma unroll
  for (int i = 0; i < 8; ++i)
    *(float4*)(ar + i * 4) = *(const float4*)(ap + i * 4);
  {
#pragma unroll
    for (int sub = 0; sub < 2; ++sub) {
      uint4 hv0, lv0, hv1, lv1;
      split8(ar + sub * 16,     hv0, lv0);
      split8(ar + sub * 16 + 8, hv1, lv1);
      const int ks = kg * 2 + sub;
      *(uint4*)&Ash[0][0][smt][ks][ 0 + sr][0] = hv0;
      *(uint4*)&Ash[0][0][smt][ks][32 + sr][0] = hv1;
      *(uint4*)&Ash[0][1][smt][ks][ 0 + sr][0] = lv0;
      *(uint4*)&Ash[0][1][smt][ks][32 + sr][0] = lv1;
    }
  }
#pragma unroll
  for (int i = 0; i < 8; ++i)
    *(float4*)(ar + i * 4) = *(const float4*)(ap + 128 + i * 4);

  short8 b[2][4];
  b[0][0] = *(const short8*)(ph0);
  b[0][1] = *(const short8*)(pl0);
  b[0][2] = *(const short8*)(ph1);
  b[0][3] = *(const short8*)(pl1);
  b[1][0] = *(const short8*)(ph0 + 512);
  b[1][1] = *(const short8*)(pl0 + 512);
  b[1][2] = *(const short8*)(ph1 + 512);
  b[1][3] = *(const short8*)(pl1 + 512);

  for (int c = 0; c < 16; ++c) {
    const int buf = c & 1;
    __syncthreads();   // buf[c&1] fully staged; prior readers of buf^1 done

#pragma unroll
    for (int ks = 0; ks < 8; ++ks) {
      const int gs = c * 8 + ks;
      short8 B0h = b[gs & 1][0], B0l = b[gs & 1][1];
      short8 B1h = b[gs & 1][2], B1l = b[gs & 1][3];
      const size_t gp = (size_t)((gs + 2 < 128) ? gs + 2 : gs) * 512;
      b[gs & 1][0] = *(const short8*)(ph0 + gp);
      b[gs & 1][1] = *(const short8*)(pl0 + gp);
      b[gs & 1][2] = *(const short8*)(ph1 + gp);
      b[gs & 1][3] = *(const short8*)(pl1 + gp);

      short8 a0h = *(const short8*)&Ash[buf][0][0][ks][l][0];
      short8 a0l = *(const short8*)&Ash[buf][1][0][ks][l][0];
      short8 a1h = *(const short8*)&Ash[buf][0][1][ks][l][0];
      short8 a1l = *(const short8*)&Ash[buf][1][1][ks][l][0];

      acc00 = mfma32(a0h, B0h, acc00);  acc01 = mfma32(a0h, B1h, acc01);
      acc10 = mfma32(a1h, B0h, acc10);  acc11 = mfma32(a1h, B1h, acc11);
      acc00 = mfma32(a0l, B0h, acc00);  acc01 = mfma32(a0l, B1h, acc01);
      acc10 = mfma32(a1l, B0h, acc10);  acc11 = mfma32(a1l, B1h, acc11);
      acc00 = mfma32(a0h, B0l, acc00);  acc01 = mfma32(a0h, B1l, acc01);
      acc10 = mfma32(a1h, B0l, acc10);  acc11 = mfma32(a1h, B1l, acc11);
    }

    if (c < 15) {
      // stage chunk c+1 (regs landed a full chunk ago) into the other buffer
#pragma unroll
      for (int sub = 0; sub < 2; ++sub) {
        uint4 hv0, lv0, hv1, lv1;
        split8(ar + sub * 16,     hv0, lv0);
        split8(ar + sub * 16 + 8, hv1, lv1);
        const int ks = kg * 2 + sub;
        *(uint4*)&Ash[buf ^ 1][0][smt][ks][ 0 + sr][0] = hv0;
        *(uint4*)&Ash[buf ^ 1][0][smt][ks][32 + sr][0] = hv1;
        *(uint4*)&Ash[buf ^ 1][1][smt][ks][ 0 + sr][0] = lv0;
        *(uint4*)&Ash[buf ^ 1][1][smt][ks][32 + sr][0] = lv1;
      }
      // issue chunk c+2 loads: a full chunk of compute to land
      const size_t ko = (size_t)((c + 2 < 16) ? c + 2 : 15) * 128;
#pragma unroll
      for (int i = 0; i < 8; ++i)
        *(float4*)(ar + i * 4) = *(const float4*)(ap + ko + i * 4);
    }
  }

  // epilogue: 32x32 C/D layout col=lane&31, row=(r&3)+8*(r>>2)+4*(lane>>5);
  // k-halves combine via fp32 atomics onto zeroed C.
  const int rb = band * 64 + 4 * (l >> 5);
  const int cb = w * 64 + (l & 31);
#pragma unroll
  for (int r = 0; r < 16; ++r) {
    const int row = rb + (r & 3) + 8 * (r >> 2);
    unsafeAtomicAdd(&C[(size_t)row * NE + cb],             acc00[r]);
    unsafeAtomicAdd(&C[(size_t)row * NE + cb + 32],        acc01[r]);
    unsafeAtomicAdd(&C[(size_t)(row + 32) * NE + cb],      acc10[r]);
    unsafeAtomicAdd(&C[(size_t)(row + 32) * NE + cb + 32], acc11[r]);
  }
}

// ---- softmax + biased top-8 + gather: one wave per token (passed R1-R3) ----------
__global__ __launch_bounds__(256) void topk_kernel(
    const float* __restrict__ C, const float* __restrict__ bias,
    float* __restrict__ wOut, float* __restrict__ iOut) {
  const int wave = threadIdx.x >> 6;
  const int lane = threadIdx.x & 63;
  const int tok  = blockIdx.x * 4 + wave;

  float4 c4 = *(const float4*)(C + (size_t)tok * NE + lane * 4);
  float v[4] = {c4.x, c4.y, c4.z, c4.w};

  float mx = fmaxf(fmaxf(v[0], v[1]), fmaxf(v[2], v[3]));
#pragma unroll
  for (int off = 32; off >= 1; off >>= 1) mx = fmaxf(mx, __shfl_xor(mx, off));

  float e0 = __expf(v[0] - mx), e1 = __expf(v[1] - mx);
  float e2 = __expf(v[2] - mx), e3 = __expf(v[3] - mx);
  float sum = e0 + e1 + e2 + e3;
#pragma unroll
  for (int off = 32; off >= 1; off >>= 1) sum += __shfl_xor(sum, off);

  float sc0 = e0 / sum, sc1 = e1 / sum, sc2 = e2 / sum, sc3 = e3 / sum;
  float4 b4 = *(const float4*)(bias + lane * 4);
  float ch0 = sc0 + b4.x, ch1 = sc1 + b4.y, ch2 = sc2 + b4.z, ch3 = sc3 + b4.w;

#pragma unroll
  for (int t = 0; t < TOPK_N; ++t) {
    float bv = ch0; int bi = 0; float bs = sc0;
    if (ch1 > bv) { bv = ch1; bi = 1; bs = sc1; }
    if (ch2 > bv) { bv = ch2; bi = 2; bs = sc2; }
    if (ch3 > bv) { bv = ch3; bi = 3; bs = sc3; }
    int be = lane * 4 + bi;
#pragma unroll
    for (int off = 32; off >= 1; off >>= 1) {
      float ov = __shfl_xor(bv, off);
      int   oe = __shfl_xor(be, off);
      float os = __shfl_xor(bs, off);
      if (ov > bv || (ov == bv && oe < be)) { bv = ov; be = oe; bs = os; }
    }
    if (lane == 0) {
      wOut[tok * TOPK_N + t] = bs * 1.5f;
      iOut[tok * TOPK_N + t] = (float)be;
    }
    bool own = (be >> 2) == lane;
    int  lb  = be & 3;
    if (own && lb == 0) ch0 = -INFINITY;
    if (own && lb == 1) ch1 = -INFINITY;
    if (own && lb == 2) ch2 = -INFINITY;
    if (own && lb == 3) ch3 = -INFINITY;
  }
}

extern "C" void kernel_launch(void* const* d_in, const int* in_sizes, int n_in,
                              void* d_out, int out_size, void* d_ws, size_t ws_size,
                              hipStream_t stream) {
  const float* hs   = (const float*)d_in[0];   // [16384, 4096] f32
  const float* W    = (const float*)d_in[1];   // [256, 4096]   f32
  const float* bias = (const float*)d_in[2];   // [256]         f32

  float* out      = (float*)d_out;
  float* classify = out;                               // 16384*256
  float* wOut     = out + (size_t)T_TOK * NE;          // 16384*8
  float* iOut     = wOut + (size_t)T_TOK * TOPK_N;     // 16384*8

  unsigned short* Whp = (unsigned short*)d_ws;         // 2 MB packed hi
  unsigned short* Wlp = Whp + (size_t)NE * DIM;        // 2 MB packed lo

  hipMemsetAsync(classify, 0, (size_t)T_TOK * NE * sizeof(float), stream);
  convert_w_kernel<<<(NE * DIM / 8) / 256, 256, 0, stream>>>(W, Whp, Wlp);
  gemm_router<<<512, 256, 0, stream>>>(hs, Whp, Wlp, classify);
  topk_kernel<<<T_TOK / 4, 256, 0, stream>>>(classify, bias, wOut, iOut);
}